// Round 1
// baseline (1514.899 us; speedup 1.0000x reference)
//
#include <hip/hip_runtime.h>
#include <stdint.h>

#pragma clang fp contract(off)

#define NCLS   20
#define NA     5
#define NB     16
#define Hg     26
#define Wg     26
#define HWc    (Hg*Wg)            // 676
#define NBOX   (NA*HWc)           // 3380
#define NPAD   4096
#define NWRD   (NPAD/64)          // 64
#define PROBC  (NCLS+1)           // 21
#define PRE_TH 0.005f
#define NMS_TH 0.45f

__constant__ float c_bias[10] = {1.08f,1.19f,3.42f,4.41f,6.63f,11.38f,9.42f,5.11f,16.62f,10.52f};

// ---------------------------------------------------------------- decode ----
__global__ __launch_bounds__(256) void k_decode(const float* __restrict__ x,
                                                const float* __restrict__ im_info,
                                                float* __restrict__ out,
                                                float* __restrict__ scores) {
  int t = blockIdx.x * 256 + threadIdx.x;
  if (t >= NB * NBOX) return;
  int b  = t / NBOX;
  int n  = t - b * NBOX;
  int a  = n / HWc;
  int hw = n - a * HWc;
  int h  = hw / Wg;
  int w  = hw - h * Wg;

  const float* xb = x + (size_t)b * 125 * HWc;
  float tx = xb[(2*a  ) * HWc + hw];
  float ty = xb[(2*a+1) * HWc + hw];
  float tw = xb[(10+2*a) * HWc + hw];
  float th = xb[(11+2*a) * HWc + hw];
  float to = xb[(20+a  ) * HWc + hw];

  float sx  = 1.0f / (1.0f + expf(-tx));
  float sy  = 1.0f / (1.0f + expf(-ty));
  float obj = 1.0f / (1.0f + expf(-to));

  float cf[NCLS];
  float mx = -3.402823e38f;
#pragma unroll
  for (int c = 0; c < NCLS; ++c) {
    cf[c] = xb[(25 + c*NA + a) * HWc + hw];
    mx = fmaxf(mx, cf[c]);
  }
  float sum = 0.f;
#pragma unroll
  for (int c = 0; c < NCLS; ++c) { cf[c] = expf(cf[c] - mx); sum += cf[c]; }

  float* op = out + ((size_t)b * NBOX + n) * PROBC;
#pragma unroll
  for (int c = 0; c < NCLS; ++c) op[c] = cf[c] / sum * obj;
  op[NCLS] = 0.f;   // obj channel; NMS kernel writes kept scores later

  // box decode — replicate reference op order exactly
  float Wf = (float)Wg, Hf = (float)Hg;
  float bx = ((float)w + sx) / Wf;
  float by = ((float)h + sy) / Hf;
  float bw = c_bias[2*a]   * expf(tw) / Wf;
  float bh = c_bias[2*a+1] * expf(th) / Hf;
  float netw = Wf * 32.0f;
  float neth = Hf * 32.0f;
  float imh = im_info[0], imw = im_info[1];
  bool cond   = (netw / imw) < (neth / imh);
  float new_w = cond ? netw : (imw * neth / imh);
  float new_h = cond ? (imh * netw / imw) : neth;
  bx = (bx - (netw - new_w) * 0.5f / netw) / (new_w / netw);
  by = (by - (neth - new_h) * 0.5f / neth) / (new_h / neth);
  bw = bw * (netw / new_w);
  bh = bh * (neth / new_h);
  float X  = bx * imw, Y = by * imh, Wd = bw * imw, Hd = bh * imh;

  float* ob = out + (size_t)NB * NBOX * PROBC + ((size_t)b * NBOX + n) * 4;
  ob[0] = X; ob[1] = Y; ob[2] = Wd; ob[3] = Hd;

  scores[t] = (obj < PRE_TH) ? 0.f : obj;
}

// ------------------------------------------------------------------ sort ----
// key = (score_bits << 32) | (0xFFFFFFFF - idx): descending sort == stable argsort(-s)
__global__ __launch_bounds__(1024) void k_sort(const float* __restrict__ scores,
                                               const float* __restrict__ out,   // bbox region read
                                               float* __restrict__ sScore,
                                               int* __restrict__ sIdx,
                                               float4* __restrict__ sBox,
                                               unsigned long long* __restrict__ posm) {
  int b = blockIdx.x;
  __shared__ unsigned long long key[NPAD];

  for (int i = threadIdx.x; i < NPAD; i += 1024) {
    unsigned long long k = 0ULL;
    if (i < NBOX) {
      float s = scores[b * NBOX + i];
      unsigned int bits = __float_as_uint(s);       // s >= 0 -> monotone bits
      k = ((unsigned long long)bits << 32) | (unsigned long long)(0xFFFFFFFFu - (unsigned)i);
    }
    key[i] = k;
  }
  __syncthreads();

  for (int k = 2; k <= NPAD; k <<= 1) {
    for (int j = k >> 1; j > 0; j >>= 1) {
      for (int i = threadIdx.x; i < NPAD; i += 1024) {
        int ixj = i ^ j;
        if (ixj > i) {
          bool desc = ((i & k) == 0);
          unsigned long long a = key[i], c = key[ixj];
          bool sw = desc ? (a < c) : (a > c);
          if (sw) { key[i] = c; key[ixj] = a; }
        }
      }
      __syncthreads();
    }
  }

  const float4* outBox = (const float4*)(out + (size_t)NB * NBOX * PROBC);
  for (int i = threadIdx.x; i < NPAD; i += 1024) {
    unsigned long long k = key[i];
    float s = __uint_as_float((unsigned)(k >> 32));
    bool pos = (k >> 32) != 0ULL;                   // s > 0
    unsigned long long bal = __ballot(pos);
    if ((threadIdx.x & 63) == 0) posm[b * NWRD + (i >> 6)] = bal;
    sScore[b * NPAD + i] = s;
    int oi = (int)(0xFFFFFFFFu - (unsigned)(k & 0xFFFFFFFFu));
    sIdx[b * NPAD + i] = oi;
    float4 bx = make_float4(0.f, 0.f, 0.f, 0.f);
    if (oi >= 0 && oi < NBOX) bx = outBox[(size_t)b * NBOX + oi];
    sBox[b * NPAD + i] = bx;
  }
}

// ------------------------------------------------------------------- nms ----
__global__ __launch_bounds__(1024) void k_nms(const float* __restrict__ sScore,
                                              const int* __restrict__ sIdx,
                                              const float4* __restrict__ sBox,
                                              const unsigned long long* __restrict__ posm,
                                              float* __restrict__ out) {
  int b = blockIdx.x;
  __shared__ float x1s[NBOX], y1s[NBOX], x2s[NBOX], y2s[NBOX];
  __shared__ unsigned long long remv[NWRD];
  __shared__ int nposS;

  int tid = threadIdx.x;
  if (tid == 0) nposS = 0;
  for (int w0 = tid; w0 < NWRD; w0 += 1024) remv[w0] = ~posm[b * NWRD + w0];
  __syncthreads();
  if (tid < NWRD) atomicAdd(&nposS, __popcll(posm[b * NWRD + tid]));

  for (int i = tid; i < NBOX; i += 1024) {
    float4 bx = sBox[b * NPAD + i];
    x1s[i] = bx.x - bx.z * 0.5f;
    y1s[i] = bx.y - bx.w * 0.5f;
    x2s[i] = bx.x + bx.z * 0.5f;
    y2s[i] = bx.y + bx.w * 0.5f;
  }
  __syncthreads();

  int npos  = nposS;
  int lane  = tid & 63;
  int wid   = tid >> 6;           // 0..15
  const int nwav = 1024 >> 6;     // 16
  int NW = (npos + 63) >> 6;

  int i = 0;
  while (i < npos) {
    unsigned long long wv = remv[i >> 6] >> (i & 63);
    if (wv & 1ULL) {
      unsigned long long inv = ~wv;
      int cnt = (inv != 0ULL) ? (__ffsll((long long)inv) - 1) : (64 - (i & 63));
      i += cnt;
      continue;
    }
    // box i is kept: suppress all j > i with IoU > NMS_TH
    float bx1 = x1s[i], by1 = y1s[i], bx2 = x2s[i], by2 = y2s[i];
    float areai = (bx2 - bx1) * (by2 - by1);
    int fw = i >> 6;
    for (int wo = fw + wid; wo < NW; wo += nwav) {
      int j = (wo << 6) + lane;
      bool sup = false;
      if (j > i && j < npos) {
        float cx1 = x1s[j], cy1 = y1s[j], cx2 = x2s[j], cy2 = y2s[j];
        float iw = fminf(bx2, cx2) - fmaxf(bx1, cx1); iw = fmaxf(iw, 0.0f);
        float ih = fminf(by2, cy2) - fmaxf(by1, cy1); ih = fmaxf(ih, 0.0f);
        float inter = iw * ih;
        float areaj = (cx2 - cx1) * (cy2 - cy1);
        float iou = inter / (areai + areaj - inter + 1e-12f);
        sup = iou > NMS_TH;
      }
      unsigned long long bal = __ballot(sup);
      if (lane == 0 && bal) remv[wo] |= bal;
    }
    ++i;
    __syncthreads();
  }
  __syncthreads();

  // kept set == bits still clear (suppression only ever targets j > i)
  for (int p = tid; p < npos; p += 1024) {
    if (!((remv[p >> 6] >> (p & 63)) & 1ULL)) {
      int oi  = sIdx[b * NPAD + p];
      float s = sScore[b * NPAD + p];
      out[((size_t)b * NBOX + oi) * PROBC + NCLS] = s;
    }
  }
}

// ---------------------------------------------------------------- launch ----
extern "C" void kernel_launch(void* const* d_in, const int* in_sizes, int n_in,
                              void* d_out, int out_size, void* d_ws, size_t ws_size,
                              hipStream_t stream) {
  const float* x  = (const float*)d_in[0];
  const float* im = (const float*)d_in[1];
  float* out = (float*)d_out;

  float* scores = (float*)d_ws;                                   // NB*NBOX
  float* sScore = scores + (size_t)NB * NBOX;                     // NB*NPAD
  int*   sIdx   = (int*)(sScore + (size_t)NB * NPAD);             // NB*NPAD
  float4* sBox  = (float4*)(sIdx + (size_t)NB * NPAD);            // NB*NPAD (16B-aligned offset)
  unsigned long long* posm = (unsigned long long*)(sBox + (size_t)NB * NPAD);  // NB*NWRD

  hipLaunchKernelGGL(k_decode, dim3((NB * NBOX + 255) / 256), dim3(256), 0, stream,
                     x, im, out, scores);
  hipLaunchKernelGGL(k_sort, dim3(NB), dim3(1024), 0, stream,
                     scores, out, sScore, sIdx, sBox, posm);
  hipLaunchKernelGGL(k_nms, dim3(NB), dim3(1024), 0, stream,
                     sScore, sIdx, sBox, posm, out);
}

// Round 2
// 1066.846 us; speedup vs baseline: 1.4200x; 1.4200x over previous
//
#include <hip/hip_runtime.h>
#include <stdint.h>

#pragma clang fp contract(off)

#define NCLS   20
#define NA     5
#define NB     16
#define Hg     26
#define Wg     26
#define HWc    (Hg*Wg)            // 676
#define NBOX   (NA*HWc)           // 3380
#define NPAD   4096
#define NWRD   (NPAD/64)          // 64
#define NROW   3392               // 53*64, padded row count
#define SWRD   53                 // words covering 3380 boxes
#define PROBC  (NCLS+1)           // 21
#define PRE_TH 0.005f
#define NMS_TH 0.45f

__constant__ float c_bias[10] = {1.08f,1.19f,3.42f,4.41f,6.63f,11.38f,9.42f,5.11f,16.62f,10.52f};

// ---------------------------------------------------------------- decode ----
__global__ __launch_bounds__(256) void k_decode(const float* __restrict__ x,
                                                const float* __restrict__ im_info,
                                                float* __restrict__ out,
                                                float* __restrict__ scores) {
  int t = blockIdx.x * 256 + threadIdx.x;
  if (t >= NB * NBOX) return;
  int b  = t / NBOX;
  int n  = t - b * NBOX;
  int a  = n / HWc;
  int hw = n - a * HWc;
  int h  = hw / Wg;
  int w  = hw - h * Wg;

  const float* xb = x + (size_t)b * 125 * HWc;
  float tx = xb[(2*a  ) * HWc + hw];
  float ty = xb[(2*a+1) * HWc + hw];
  float tw = xb[(10+2*a) * HWc + hw];
  float th = xb[(11+2*a) * HWc + hw];
  float to = xb[(20+a  ) * HWc + hw];

  float sx  = 1.0f / (1.0f + expf(-tx));
  float sy  = 1.0f / (1.0f + expf(-ty));
  float obj = 1.0f / (1.0f + expf(-to));

  float cf[NCLS];
  float mx = -3.402823e38f;
#pragma unroll
  for (int c = 0; c < NCLS; ++c) {
    cf[c] = xb[(25 + c*NA + a) * HWc + hw];
    mx = fmaxf(mx, cf[c]);
  }
  float sum = 0.f;
#pragma unroll
  for (int c = 0; c < NCLS; ++c) { cf[c] = expf(cf[c] - mx); sum += cf[c]; }

  float* op = out + ((size_t)b * NBOX + n) * PROBC;
#pragma unroll
  for (int c = 0; c < NCLS; ++c) op[c] = cf[c] / sum * obj;
  op[NCLS] = 0.f;   // obj channel; scan kernel writes kept scores later

  // box decode — replicate reference op order exactly
  float Wf = (float)Wg, Hf = (float)Hg;
  float bx = ((float)w + sx) / Wf;
  float by = ((float)h + sy) / Hf;
  float bw = c_bias[2*a]   * expf(tw) / Wf;
  float bh = c_bias[2*a+1] * expf(th) / Hf;
  float netw = Wf * 32.0f;
  float neth = Hf * 32.0f;
  float imh = im_info[0], imw = im_info[1];
  bool cond   = (netw / imw) < (neth / imh);
  float new_w = cond ? netw : (imw * neth / imh);
  float new_h = cond ? (imh * netw / imw) : neth;
  bx = (bx - (netw - new_w) * 0.5f / netw) / (new_w / netw);
  by = (by - (neth - new_h) * 0.5f / neth) / (new_h / neth);
  bw = bw * (netw / new_w);
  bh = bh * (neth / new_h);
  float X  = bx * imw, Y = by * imh, Wd = bw * imw, Hd = bh * imh;

  float* ob = out + (size_t)NB * NBOX * PROBC + ((size_t)b * NBOX + n) * 4;
  ob[0] = X; ob[1] = Y; ob[2] = Wd; ob[3] = Hd;

  scores[t] = (obj < PRE_TH) ? 0.f : obj;
}

// ------------------------------------------------------------------ sort ----
// key = (score_bits << 32) | (0xFFFFFFFF - idx): descending sort == stable argsort(-s)
__global__ __launch_bounds__(1024) void k_sort(const float* __restrict__ scores,
                                               const float* __restrict__ out,   // bbox region read
                                               float* __restrict__ sScore,
                                               int* __restrict__ sIdx,
                                               float4* __restrict__ sBox,
                                               unsigned long long* __restrict__ posm) {
  int b = blockIdx.x;
  __shared__ unsigned long long key[NPAD];

  for (int i = threadIdx.x; i < NPAD; i += 1024) {
    unsigned long long k = 0ULL;
    if (i < NBOX) {
      float s = scores[b * NBOX + i];
      unsigned int bits = __float_as_uint(s);       // s >= 0 -> monotone bits
      k = ((unsigned long long)bits << 32) | (unsigned long long)(0xFFFFFFFFu - (unsigned)i);
    }
    key[i] = k;
  }
  __syncthreads();

  for (int k = 2; k <= NPAD; k <<= 1) {
    for (int j = k >> 1; j > 0; j >>= 1) {
      for (int i = threadIdx.x; i < NPAD; i += 1024) {
        int ixj = i ^ j;
        if (ixj > i) {
          bool desc = ((i & k) == 0);
          unsigned long long a = key[i], c = key[ixj];
          bool sw = desc ? (a < c) : (a > c);
          if (sw) { key[i] = c; key[ixj] = a; }
        }
      }
      __syncthreads();
    }
  }

  const float4* outBox = (const float4*)(out + (size_t)NB * NBOX * PROBC);
  for (int i = threadIdx.x; i < NPAD; i += 1024) {
    unsigned long long k = key[i];
    float s = __uint_as_float((unsigned)(k >> 32));
    bool pos = (k >> 32) != 0ULL;                   // s > 0
    unsigned long long bal = __ballot(pos);
    if ((threadIdx.x & 63) == 0) posm[b * NWRD + (i >> 6)] = bal;
    sScore[b * NPAD + i] = s;
    int oi = (int)(0xFFFFFFFFu - (unsigned)(k & 0xFFFFFFFFu));
    sIdx[b * NPAD + i] = oi;
    float4 bx = make_float4(0.f, 0.f, 0.f, 0.f);
    if (oi >= 0 && oi < NBOX) bx = outBox[(size_t)b * NBOX + oi];
    sBox[b * NPAD + i] = bx;
  }
}

// ---------------------------------------------------------------- supmat ----
// Parallel all-pairs suppression bitmask: supmat[b][row][w] bit l = (j=w*64+l)
// strictly after row in sorted order AND IoU(row,j) > NMS_TH.
// Also: rowmask[b][row] = bitmask of nonzero words; diagm[b][c][l] = word c of
// row c*64+l (coalesced diagonal blocks for the scan).
__global__ __launch_bounds__(256) void k_supmat(const float4* __restrict__ sBox,
                                                unsigned long long* __restrict__ supmat,
                                                unsigned long long* __restrict__ rowmask,
                                                unsigned long long* __restrict__ diagm) {
  int b    = blockIdx.x;
  int rowg = blockIdx.y;          // 0..SWRD-1, block of 64 rows
  __shared__ float x1s[NROW], y1s[NROW], x2s[NROW], y2s[NROW];
  __shared__ unsigned long long rmaskS[64];
  int tid = threadIdx.x;
  if (tid < 64) rmaskS[tid] = 0ULL;
  for (int i = tid; i < NROW; i += 256) {
    float4 bx = sBox[(size_t)b * NPAD + i];
    x1s[i] = bx.x - bx.z * 0.5f;
    y1s[i] = bx.y - bx.w * 0.5f;
    x2s[i] = bx.x + bx.z * 0.5f;
    y2s[i] = bx.y + bx.w * 0.5f;
  }
  __syncthreads();

  unsigned long long* smB = supmat + (size_t)b * NROW * SWRD;
  for (int task = tid; task < 64 * SWRD; task += 256) {
    int r = task / SWRD;
    int w = task - r * SWRD;
    int row = rowg * 64 + r;
    unsigned long long bits = 0ULL;
    int base = w * 64;
    if (base + 63 > row) {                       // word has at least one j > row
      float bx1 = x1s[row], by1 = y1s[row], bx2 = x2s[row], by2 = y2s[row];
      float areai = (bx2 - bx1) * (by2 - by1);
      for (int t2 = 0; t2 < 64; ++t2) {
        int j = base + t2;
        if (j > row) {
          float cx1 = x1s[j], cy1 = y1s[j], cx2 = x2s[j], cy2 = y2s[j];
          float iw = fminf(bx2, cx2) - fmaxf(bx1, cx1); iw = fmaxf(iw, 0.0f);
          float ih = fminf(by2, cy2) - fmaxf(by1, cy1); ih = fmaxf(ih, 0.0f);
          float inter = iw * ih;
          float areaj = (cx2 - cx1) * (cy2 - cy1);
          float iou = inter / (areai + areaj - inter + 1e-12f);
          if (iou > NMS_TH) bits |= 1ULL << t2;
        }
      }
    }
    smB[(size_t)row * SWRD + w] = bits;
    if (w == rowg) diagm[((size_t)b * SWRD + rowg) * 64 + r] = bits;
    if (bits) atomicOr(&rmaskS[r], 1ULL << w);
  }
  __syncthreads();
  if (tid < 64) rowmask[(size_t)b * NROW + rowg * 64 + tid] = rmaskS[tid];
}

// ------------------------------------------------------------------ scan ----
// Greedy NMS over precomputed bitmasks. One wave per batch; 53 chunk steps.
__global__ __launch_bounds__(64) void k_scan(const unsigned long long* __restrict__ supmat,
                                             const unsigned long long* __restrict__ rowmask,
                                             const unsigned long long* __restrict__ diagm,
                                             const unsigned long long* __restrict__ posm,
                                             const float* __restrict__ sScore,
                                             const int* __restrict__ sIdx,
                                             float* __restrict__ out) {
  int b = blockIdx.x;
  int l = threadIdx.x;            // 0..63
  __shared__ unsigned long long remv[SWRD];
  if (l < SWRD) remv[l] = ~posm[b * NWRD + l];   // bit set = suppressed/invalid
  __syncthreads();

  const unsigned long long* sm  = supmat + (size_t)b * NROW * SWRD;
  const unsigned long long* rmB = rowmask + (size_t)b * NROW;
  const unsigned long long* dgB = diagm + (size_t)b * SWRD * 64;

  for (int c = 0; c < SWRD; ++c) {
    int row = c * 64 + l;
    unsigned long long diag = dgB[c * 64 + l];      // coalesced
    unsigned long long rm   = rmB[row];             // coalesced
    unsigned long long cur  = remv[c];              // same-address broadcast

    // intra-chunk greedy resolve (skipped when no intra-chunk suppression)
    if (__ballot(diag != 0ULL)) {
      for (int k = 0; k < 64; ++k) {
        unsigned long long dk = __shfl(diag, k);
        if (!((cur >> k) & 1ULL)) cur |= dk;
      }
    }
    if (l == 0) remv[c] = cur;

    // propagate kept rows' suppression bits to later words (sparse)
    unsigned long long above = (rm >> (c + 1)) << (c + 1);
    bool act = (!((cur >> l) & 1ULL)) && (above != 0ULL);
    if (act) {
      unsigned long long m = above;
      while (m) {
        int w = __ffsll((long long)m) - 1;
        m &= m - 1;
        atomicOr(&remv[w], sm[(size_t)row * SWRD + w]);
      }
    }
    __syncthreads();
  }

  // kept set == bits still clear
  for (int c = 0; c < SWRD; ++c) {
    int p = c * 64 + l;
    if (p < NBOX && !((remv[c] >> l) & 1ULL)) {
      int oi  = sIdx[b * NPAD + p];
      float s = sScore[b * NPAD + p];
      out[((size_t)b * NBOX + oi) * PROBC + NCLS] = s;
    }
  }
}

// --------------------------------------------------- fallback serial nms ----
__global__ __launch_bounds__(1024) void k_nms(const float* __restrict__ sScore,
                                              const int* __restrict__ sIdx,
                                              const float4* __restrict__ sBox,
                                              const unsigned long long* __restrict__ posm,
                                              float* __restrict__ out) {
  int b = blockIdx.x;
  __shared__ float x1s[NBOX], y1s[NBOX], x2s[NBOX], y2s[NBOX];
  __shared__ unsigned long long remv[NWRD];
  __shared__ int nposS;

  int tid = threadIdx.x;
  if (tid == 0) nposS = 0;
  for (int w0 = tid; w0 < NWRD; w0 += 1024) remv[w0] = ~posm[b * NWRD + w0];
  __syncthreads();
  if (tid < NWRD) atomicAdd(&nposS, __popcll(posm[b * NWRD + tid]));

  for (int i = tid; i < NBOX; i += 1024) {
    float4 bx = sBox[b * NPAD + i];
    x1s[i] = bx.x - bx.z * 0.5f;
    y1s[i] = bx.y - bx.w * 0.5f;
    x2s[i] = bx.x + bx.z * 0.5f;
    y2s[i] = bx.y + bx.w * 0.5f;
  }
  __syncthreads();

  int npos  = nposS;
  int lane  = tid & 63;
  int wid   = tid >> 6;
  const int nwav = 1024 >> 6;
  int NW = (npos + 63) >> 6;

  int i = 0;
  while (i < npos) {
    unsigned long long wv = remv[i >> 6] >> (i & 63);
    if (wv & 1ULL) {
      unsigned long long inv = ~wv;
      int cnt = (inv != 0ULL) ? (__ffsll((long long)inv) - 1) : (64 - (i & 63));
      i += cnt;
      continue;
    }
    float bx1 = x1s[i], by1 = y1s[i], bx2 = x2s[i], by2 = y2s[i];
    float areai = (bx2 - bx1) * (by2 - by1);
    int fw = i >> 6;
    for (int wo = fw + wid; wo < NW; wo += nwav) {
      int j = (wo << 6) + lane;
      bool sup = false;
      if (j > i && j < npos) {
        float cx1 = x1s[j], cy1 = y1s[j], cx2 = x2s[j], cy2 = y2s[j];
        float iw = fminf(bx2, cx2) - fmaxf(bx1, cx1); iw = fmaxf(iw, 0.0f);
        float ih = fminf(by2, cy2) - fmaxf(by1, cy1); ih = fmaxf(ih, 0.0f);
        float inter = iw * ih;
        float areaj = (cx2 - cx1) * (cy2 - cy1);
        float iou = inter / (areai + areaj - inter + 1e-12f);
        sup = iou > NMS_TH;
      }
      unsigned long long bal = __ballot(sup);
      if (lane == 0 && bal) remv[wo] |= bal;
    }
    ++i;
    __syncthreads();
  }
  __syncthreads();

  for (int p = tid; p < npos; p += 1024) {
    if (!((remv[p >> 6] >> (p & 63)) & 1ULL)) {
      int oi  = sIdx[b * NPAD + p];
      float s = sScore[b * NPAD + p];
      out[((size_t)b * NBOX + oi) * PROBC + NCLS] = s;
    }
  }
}

// ---------------------------------------------------------------- launch ----
extern "C" void kernel_launch(void* const* d_in, const int* in_sizes, int n_in,
                              void* d_out, int out_size, void* d_ws, size_t ws_size,
                              hipStream_t stream) {
  const float* x  = (const float*)d_in[0];
  const float* im = (const float*)d_in[1];
  float* out = (float*)d_out;

  float* scores = (float*)d_ws;                                   // NB*NBOX
  float* sScore = scores + (size_t)NB * NBOX;                     // NB*NPAD
  int*   sIdx   = (int*)(sScore + (size_t)NB * NPAD);             // NB*NPAD
  float4* sBox  = (float4*)(sIdx + (size_t)NB * NPAD);            // NB*NPAD (16B-aligned)
  unsigned long long* posm   = (unsigned long long*)(sBox + (size_t)NB * NPAD); // NB*NWRD
  unsigned long long* supmat = posm + (size_t)NB * NWRD;          // NB*NROW*SWRD
  unsigned long long* rowmask = supmat + (size_t)NB * NROW * SWRD; // NB*NROW
  unsigned long long* diagm  = rowmask + (size_t)NB * NROW;       // NB*SWRD*64
  size_t need = (size_t)((char*)(diagm + (size_t)NB * SWRD * 64) - (char*)d_ws);

  hipLaunchKernelGGL(k_decode, dim3((NB * NBOX + 255) / 256), dim3(256), 0, stream,
                     x, im, out, scores);
  hipLaunchKernelGGL(k_sort, dim3(NB), dim3(1024), 0, stream,
                     scores, out, sScore, sIdx, sBox, posm);
  if (ws_size >= need) {
    hipLaunchKernelGGL(k_supmat, dim3(NB, SWRD), dim3(256), 0, stream,
                       sBox, supmat, rowmask, diagm);
    hipLaunchKernelGGL(k_scan, dim3(NB), dim3(64), 0, stream,
                       supmat, rowmask, diagm, posm, sScore, sIdx, out);
  } else {
    hipLaunchKernelGGL(k_nms, dim3(NB), dim3(1024), 0, stream,
                       sScore, sIdx, sBox, posm, out);
  }
}

// Round 3
// 448.615 us; speedup vs baseline: 3.3768x; 2.3781x over previous
//
#include <hip/hip_runtime.h>
#include <stdint.h>

#pragma clang fp contract(off)

#define NCLS   20
#define NA     5
#define NB     16
#define Hg     26
#define Wg     26
#define HWc    (Hg*Wg)            // 676
#define NBOX   (NA*HWc)           // 3380
#define NPAD   4096
#define NWRD   (NPAD/64)          // 64
#define NROW   3392               // 53*64, padded row count
#define SWRD   53                 // words covering 3380 boxes
#define PROBC  (NCLS+1)           // 21
#define PRE_TH 0.005f
#define NMS_TH 0.45f

__constant__ float c_bias[10] = {1.08f,1.19f,3.42f,4.41f,6.63f,11.38f,9.42f,5.11f,16.62f,10.52f};

// ---------------------------------------------------------------- decode ----
__global__ __launch_bounds__(256) void k_decode(const float* __restrict__ x,
                                                const float* __restrict__ im_info,
                                                float* __restrict__ out,
                                                float* __restrict__ scores) {
  int t = blockIdx.x * 256 + threadIdx.x;
  if (t >= NB * NBOX) return;
  int b  = t / NBOX;
  int n  = t - b * NBOX;
  int a  = n / HWc;
  int hw = n - a * HWc;
  int h  = hw / Wg;
  int w  = hw - h * Wg;

  const float* xb = x + (size_t)b * 125 * HWc;
  float tx = xb[(2*a  ) * HWc + hw];
  float ty = xb[(2*a+1) * HWc + hw];
  float tw = xb[(10+2*a) * HWc + hw];
  float th = xb[(11+2*a) * HWc + hw];
  float to = xb[(20+a  ) * HWc + hw];

  float sx  = 1.0f / (1.0f + expf(-tx));
  float sy  = 1.0f / (1.0f + expf(-ty));
  float obj = 1.0f / (1.0f + expf(-to));

  float cf[NCLS];
  float mx = -3.402823e38f;
#pragma unroll
  for (int c = 0; c < NCLS; ++c) {
    cf[c] = xb[(25 + c*NA + a) * HWc + hw];
    mx = fmaxf(mx, cf[c]);
  }
  float sum = 0.f;
#pragma unroll
  for (int c = 0; c < NCLS; ++c) { cf[c] = expf(cf[c] - mx); sum += cf[c]; }

  float* op = out + ((size_t)b * NBOX + n) * PROBC;
#pragma unroll
  for (int c = 0; c < NCLS; ++c) op[c] = cf[c] / sum * obj;
  op[NCLS] = 0.f;   // obj channel; scan kernel writes kept scores later

  // box decode — replicate reference op order exactly
  float Wf = (float)Wg, Hf = (float)Hg;
  float bx = ((float)w + sx) / Wf;
  float by = ((float)h + sy) / Hf;
  float bw = c_bias[2*a]   * expf(tw) / Wf;
  float bh = c_bias[2*a+1] * expf(th) / Hf;
  float netw = Wf * 32.0f;
  float neth = Hf * 32.0f;
  float imh = im_info[0], imw = im_info[1];
  bool cond   = (netw / imw) < (neth / imh);
  float new_w = cond ? netw : (imw * neth / imh);
  float new_h = cond ? (imh * netw / imw) : neth;
  bx = (bx - (netw - new_w) * 0.5f / netw) / (new_w / netw);
  by = (by - (neth - new_h) * 0.5f / neth) / (new_h / neth);
  bw = bw * (netw / new_w);
  bh = bh * (neth / new_h);
  float X  = bx * imw, Y = by * imh, Wd = bw * imw, Hd = bh * imh;

  float* ob = out + (size_t)NB * NBOX * PROBC + ((size_t)b * NBOX + n) * 4;
  ob[0] = X; ob[1] = Y; ob[2] = Wd; ob[3] = Hd;

  scores[t] = (obj < PRE_TH) ? 0.f : obj;
}

// ------------------------------------------------------------------ sort ----
// key = (score_bits << 32) | (0xFFFFFFFF - idx): descending sort == stable argsort(-s)
// Also zeroes rowmask for this batch (must complete before k_supmat — stream order).
__global__ __launch_bounds__(1024) void k_sort(const float* __restrict__ scores,
                                               const float* __restrict__ out,   // bbox region read
                                               float* __restrict__ sScore,
                                               int* __restrict__ sIdx,
                                               float4* __restrict__ sBox,
                                               unsigned long long* __restrict__ posm,
                                               unsigned long long* __restrict__ rowmask) {
  int b = blockIdx.x;
  __shared__ unsigned long long key[NPAD];

  for (int i = threadIdx.x; i < NROW; i += 1024) rowmask[(size_t)b * NROW + i] = 0ULL;

  for (int i = threadIdx.x; i < NPAD; i += 1024) {
    unsigned long long k = 0ULL;
    if (i < NBOX) {
      float s = scores[b * NBOX + i];
      unsigned int bits = __float_as_uint(s);       // s >= 0 -> monotone bits
      k = ((unsigned long long)bits << 32) | (unsigned long long)(0xFFFFFFFFu - (unsigned)i);
    }
    key[i] = k;
  }
  __syncthreads();

  for (int k = 2; k <= NPAD; k <<= 1) {
    for (int j = k >> 1; j > 0; j >>= 1) {
      for (int i = threadIdx.x; i < NPAD; i += 1024) {
        int ixj = i ^ j;
        if (ixj > i) {
          bool desc = ((i & k) == 0);
          unsigned long long a = key[i], c = key[ixj];
          bool sw = desc ? (a < c) : (a > c);
          if (sw) { key[i] = c; key[ixj] = a; }
        }
      }
      __syncthreads();
    }
  }

  const float4* outBox = (const float4*)(out + (size_t)NB * NBOX * PROBC);
  for (int i = threadIdx.x; i < NPAD; i += 1024) {
    unsigned long long k = key[i];
    float s = __uint_as_float((unsigned)(k >> 32));
    bool pos = (k >> 32) != 0ULL;                   // s > 0
    unsigned long long bal = __ballot(pos);
    if ((threadIdx.x & 63) == 0) posm[b * NWRD + (i >> 6)] = bal;
    sScore[b * NPAD + i] = s;
    int oi = (int)(0xFFFFFFFFu - (unsigned)(k & 0xFFFFFFFFu));
    sIdx[b * NPAD + i] = oi;
    float4 bx = make_float4(0.f, 0.f, 0.f, 0.f);
    if (oi >= 0 && oi < NBOX) bx = outBox[(size_t)b * NBOX + oi];
    sBox[b * NPAD + i] = bx;
  }
}

// ---------------------------------------------------------------- supmat ----
// Torchvision-style all-pairs suppression bitmask, one thread per ROW, inner
// loop over the col-block's 64 boxes staged in LDS (broadcast reads, no bank
// conflicts). Transposed layout: supmatT[b][w][row] — coalesced stores, and
// the diagonal word is a naturally coalesced read for the scan.
__global__ __launch_bounds__(64) void k_supmat(const float4* __restrict__ sBox,
                                               unsigned long long* __restrict__ supmatT,
                                               unsigned long long* __restrict__ rowmask) {
  int colg = blockIdx.x;
  int rowg = blockIdx.y;
  if (colg < rowg) return;                          // strictly-lower blocks never read
  int b = blockIdx.z;
  int l = threadIdx.x;                              // 0..63

  __shared__ float4 corn[64];                       // col corners x1,y1,x2,y2
  __shared__ float  car[64];                        // col areas

  float4 cb = sBox[(size_t)b * NPAD + colg * 64 + l];
  float c1 = cb.x - cb.z * 0.5f;
  float d1 = cb.y - cb.w * 0.5f;
  float c2 = cb.x + cb.z * 0.5f;
  float d2 = cb.y + cb.w * 0.5f;
  corn[l] = make_float4(c1, d1, c2, d2);
  car[l]  = (c2 - c1) * (d2 - d1);
  __syncthreads();

  int row = rowg * 64 + l;
  float4 rb = sBox[(size_t)b * NPAD + row];
  float bx1 = rb.x - rb.z * 0.5f;
  float by1 = rb.y - rb.w * 0.5f;
  float bx2 = rb.x + rb.z * 0.5f;
  float by2 = rb.y + rb.w * 0.5f;
  float areai = (bx2 - bx1) * (by2 - by1);

  int jmin = row - colg * 64;                       // bits t2 > jmin are j > row
  unsigned long long bits = 0ULL;
#pragma unroll 4
  for (int t2 = 0; t2 < 64; ++t2) {
    float4 cc = corn[t2];                           // broadcast — conflict-free
    float aj  = car[t2];
    float iw = fminf(bx2, cc.z) - fmaxf(bx1, cc.x); iw = fmaxf(iw, 0.0f);
    float ih = fminf(by2, cc.w) - fmaxf(by1, cc.y); ih = fmaxf(ih, 0.0f);
    float inter = iw * ih;
    float iou = inter / (areai + aj - inter + 1e-12f);
    if ((iou > NMS_TH) & (t2 > jmin)) bits |= 1ULL << t2;
  }

  supmatT[((size_t)b * SWRD + colg) * NROW + row] = bits;   // coalesced
  if (bits && colg > rowg)
    atomicOr(&rowmask[(size_t)b * NROW + row], 1ULL << colg);
}

// ------------------------------------------------------------------ scan ----
// Greedy NMS over precomputed bitmasks. One wave per batch; 53 chunk steps.
__global__ __launch_bounds__(64) void k_scan(const unsigned long long* __restrict__ supmatT,
                                             const unsigned long long* __restrict__ rowmask,
                                             const unsigned long long* __restrict__ posm,
                                             const float* __restrict__ sScore,
                                             const int* __restrict__ sIdx,
                                             float* __restrict__ out) {
  int b = blockIdx.x;
  int l = threadIdx.x;            // 0..63
  __shared__ unsigned long long remv[SWRD];
  if (l < SWRD) remv[l] = ~posm[b * NWRD + l];   // bit set = suppressed/invalid
  __syncthreads();

  const unsigned long long* smT = supmatT + (size_t)b * SWRD * NROW;
  const unsigned long long* rmB = rowmask + (size_t)b * NROW;

  for (int c = 0; c < SWRD; ++c) {
    int row = c * 64 + l;
    unsigned long long diag = smT[(size_t)c * NROW + row];   // coalesced
    unsigned long long rm   = rmB[row];                      // coalesced
    unsigned long long cur  = remv[c];                       // broadcast

    // intra-chunk greedy resolve (skipped when no intra-chunk suppression)
    if (__ballot(diag != 0ULL)) {
      for (int k = 0; k < 64; ++k) {
        unsigned long long dk = __shfl(diag, k);
        if (!((cur >> k) & 1ULL)) cur |= dk;
      }
    }
    if (l == 0) remv[c] = cur;

    // propagate kept rows' suppression bits to later words (sparse)
    unsigned long long above = (rm >> (c + 1)) << (c + 1);
    bool act = (!((cur >> l) & 1ULL)) && (above != 0ULL);
    if (act) {
      unsigned long long m = above;
      while (m) {
        int w = __ffsll((long long)m) - 1;
        m &= m - 1;
        atomicOr(&remv[w], smT[(size_t)w * NROW + row]);
      }
    }
    __syncthreads();
  }

  // kept set == bits still clear
  for (int c = 0; c < SWRD; ++c) {
    int p = c * 64 + l;
    if (p < NBOX && !((remv[c] >> l) & 1ULL)) {
      int oi  = sIdx[b * NPAD + p];
      float s = sScore[b * NPAD + p];
      out[((size_t)b * NBOX + oi) * PROBC + NCLS] = s;
    }
  }
}

// ---------------------------------------------------------------- launch ----
extern "C" void kernel_launch(void* const* d_in, const int* in_sizes, int n_in,
                              void* d_out, int out_size, void* d_ws, size_t ws_size,
                              hipStream_t stream) {
  const float* x  = (const float*)d_in[0];
  const float* im = (const float*)d_in[1];
  float* out = (float*)d_out;

  float* scores = (float*)d_ws;                                   // NB*NBOX
  float* sScore = scores + (size_t)NB * NBOX;                     // NB*NPAD
  int*   sIdx   = (int*)(sScore + (size_t)NB * NPAD);             // NB*NPAD
  float4* sBox  = (float4*)(sIdx + (size_t)NB * NPAD);            // NB*NPAD (16B-aligned)
  unsigned long long* posm    = (unsigned long long*)(sBox + (size_t)NB * NPAD); // NB*NWRD
  unsigned long long* supmatT = posm + (size_t)NB * NWRD;         // NB*SWRD*NROW
  unsigned long long* rowmask = supmatT + (size_t)NB * SWRD * NROW; // NB*NROW

  hipLaunchKernelGGL(k_decode, dim3((NB * NBOX + 255) / 256), dim3(256), 0, stream,
                     x, im, out, scores);
  hipLaunchKernelGGL(k_sort, dim3(NB), dim3(1024), 0, stream,
                     scores, out, sScore, sIdx, sBox, posm, rowmask);
  hipLaunchKernelGGL(k_supmat, dim3(SWRD, SWRD, NB), dim3(64), 0, stream,
                     sBox, supmatT, rowmask);
  hipLaunchKernelGGL(k_scan, dim3(NB), dim3(64), 0, stream,
                     supmatT, rowmask, posm, sScore, sIdx, out);
}

// Round 4
// 364.569 us; speedup vs baseline: 4.1553x; 1.2305x over previous
//
#include <hip/hip_runtime.h>
#include <stdint.h>

#pragma clang fp contract(off)

#define NCLS   20
#define NA     5
#define NB     16
#define Hg     26
#define Wg     26
#define HWc    (Hg*Wg)            // 676
#define NBOX   (NA*HWc)           // 3380
#define NPAD   4096
#define NWRD   (NPAD/64)          // 64
#define NROW   3392               // 53*64, padded row count
#define SWRD   53                 // words covering 3380 boxes
#define PROBC  (NCLS+1)           // 21
#define PRE_TH 0.005f
#define NMS_TH 0.45f

__constant__ float c_bias[10] = {1.08f,1.19f,3.42f,4.41f,6.63f,11.38f,9.42f,5.11f,16.62f,10.52f};

// ---------------------------------------------------------------- decode ----
__global__ __launch_bounds__(256) void k_decode(const float* __restrict__ x,
                                                const float* __restrict__ im_info,
                                                float* __restrict__ out,
                                                float* __restrict__ scores) {
  int t = blockIdx.x * 256 + threadIdx.x;
  if (t >= NB * NBOX) return;
  int b  = t / NBOX;
  int n  = t - b * NBOX;
  int a  = n / HWc;
  int hw = n - a * HWc;
  int h  = hw / Wg;
  int w  = hw - h * Wg;

  const float* xb = x + (size_t)b * 125 * HWc;
  float tx = xb[(2*a  ) * HWc + hw];
  float ty = xb[(2*a+1) * HWc + hw];
  float tw = xb[(10+2*a) * HWc + hw];
  float th = xb[(11+2*a) * HWc + hw];
  float to = xb[(20+a  ) * HWc + hw];

  float sx  = 1.0f / (1.0f + expf(-tx));
  float sy  = 1.0f / (1.0f + expf(-ty));
  float obj = 1.0f / (1.0f + expf(-to));

  float cf[NCLS];
  float mx = -3.402823e38f;
#pragma unroll
  for (int c = 0; c < NCLS; ++c) {
    cf[c] = xb[(25 + c*NA + a) * HWc + hw];
    mx = fmaxf(mx, cf[c]);
  }
  float sum = 0.f;
#pragma unroll
  for (int c = 0; c < NCLS; ++c) { cf[c] = expf(cf[c] - mx); sum += cf[c]; }

  float* op = out + ((size_t)b * NBOX + n) * PROBC;
#pragma unroll
  for (int c = 0; c < NCLS; ++c) op[c] = cf[c] / sum * obj;
  op[NCLS] = 0.f;   // obj channel; scan kernel writes kept scores later

  // box decode — replicate reference op order exactly
  float Wf = (float)Wg, Hf = (float)Hg;
  float bx = ((float)w + sx) / Wf;
  float by = ((float)h + sy) / Hf;
  float bw = c_bias[2*a]   * expf(tw) / Wf;
  float bh = c_bias[2*a+1] * expf(th) / Hf;
  float netw = Wf * 32.0f;
  float neth = Hf * 32.0f;
  float imh = im_info[0], imw = im_info[1];
  bool cond   = (netw / imw) < (neth / imh);
  float new_w = cond ? netw : (imw * neth / imh);
  float new_h = cond ? (imh * netw / imw) : neth;
  bx = (bx - (netw - new_w) * 0.5f / netw) / (new_w / netw);
  by = (by - (neth - new_h) * 0.5f / neth) / (new_h / neth);
  bw = bw * (netw / new_w);
  bh = bh * (neth / new_h);
  float X  = bx * imw, Y = by * imh, Wd = bw * imw, Hd = bh * imh;

  float* ob = out + (size_t)NB * NBOX * PROBC + ((size_t)b * NBOX + n) * 4;
  ob[0] = X; ob[1] = Y; ob[2] = Wd; ob[3] = Hd;

  scores[t] = (obj < PRE_TH) ? 0.f : obj;
}

// ------------------------------------------------------------------ sort ----
// key = (score_bits << 32) | (0xFFFFFFFF - idx): descending sort == stable argsort(-s)
// Also zeroes rowmask for this batch (completes before k_supmat — stream order).
__global__ __launch_bounds__(1024) void k_sort(const float* __restrict__ scores,
                                               const float* __restrict__ out,   // bbox region read
                                               float* __restrict__ sScore,
                                               int* __restrict__ sIdx,
                                               float4* __restrict__ sBox,
                                               unsigned long long* __restrict__ posm,
                                               unsigned long long* __restrict__ rowmask) {
  int b = blockIdx.x;
  __shared__ unsigned long long key[NPAD];

  for (int i = threadIdx.x; i < NROW; i += 1024) rowmask[(size_t)b * NROW + i] = 0ULL;

  for (int i = threadIdx.x; i < NPAD; i += 1024) {
    unsigned long long k = 0ULL;
    if (i < NBOX) {
      float s = scores[b * NBOX + i];
      unsigned int bits = __float_as_uint(s);       // s >= 0 -> monotone bits
      k = ((unsigned long long)bits << 32) | (unsigned long long)(0xFFFFFFFFu - (unsigned)i);
    }
    key[i] = k;
  }
  __syncthreads();

  for (int k = 2; k <= NPAD; k <<= 1) {
    for (int j = k >> 1; j > 0; j >>= 1) {
      for (int i = threadIdx.x; i < NPAD; i += 1024) {
        int ixj = i ^ j;
        if (ixj > i) {
          bool desc = ((i & k) == 0);
          unsigned long long a = key[i], c = key[ixj];
          bool sw = desc ? (a < c) : (a > c);
          if (sw) { key[i] = c; key[ixj] = a; }
        }
      }
      __syncthreads();
    }
  }

  const float4* outBox = (const float4*)(out + (size_t)NB * NBOX * PROBC);
  for (int i = threadIdx.x; i < NPAD; i += 1024) {
    unsigned long long k = key[i];
    float s = __uint_as_float((unsigned)(k >> 32));
    bool pos = (k >> 32) != 0ULL;                   // s > 0
    unsigned long long bal = __ballot(pos);
    if ((threadIdx.x & 63) == 0) posm[b * NWRD + (i >> 6)] = bal;
    sScore[b * NPAD + i] = s;
    int oi = (int)(0xFFFFFFFFu - (unsigned)(k & 0xFFFFFFFFu));
    sIdx[b * NPAD + i] = oi;
    float4 bx = make_float4(0.f, 0.f, 0.f, 0.f);
    if (oi >= 0 && oi < NBOX) bx = outBox[(size_t)b * NBOX + oi];
    sBox[b * NPAD + i] = bx;
  }
}

// ---------------------------------------------------------------- supmat ----
// One thread per ROW, inner loop over the col-block's 64 boxes staged in LDS
// (broadcast reads, conflict-free). Transposed layout supmatT[b][w][row]:
// coalesced stores; diagonal word is a coalesced read for the scan.
__global__ __launch_bounds__(64) void k_supmat(const float4* __restrict__ sBox,
                                               unsigned long long* __restrict__ supmatT,
                                               unsigned long long* __restrict__ rowmask) {
  int colg = blockIdx.x;
  int rowg = blockIdx.y;
  if (colg < rowg) return;                          // strictly-lower blocks never read
  int b = blockIdx.z;
  int l = threadIdx.x;                              // 0..63

  __shared__ float4 corn[64];                       // col corners x1,y1,x2,y2
  __shared__ float  car[64];                        // col areas

  float4 cb = sBox[(size_t)b * NPAD + colg * 64 + l];
  float c1 = cb.x - cb.z * 0.5f;
  float d1 = cb.y - cb.w * 0.5f;
  float c2 = cb.x + cb.z * 0.5f;
  float d2 = cb.y + cb.w * 0.5f;
  corn[l] = make_float4(c1, d1, c2, d2);
  car[l]  = (c2 - c1) * (d2 - d1);
  __syncthreads();

  int row = rowg * 64 + l;
  float4 rb = sBox[(size_t)b * NPAD + row];
  float bx1 = rb.x - rb.z * 0.5f;
  float by1 = rb.y - rb.w * 0.5f;
  float bx2 = rb.x + rb.z * 0.5f;
  float by2 = rb.y + rb.w * 0.5f;
  float areai = (bx2 - bx1) * (by2 - by1);

  int jmin = row - colg * 64;                       // bits t2 > jmin are j > row
  unsigned long long bits = 0ULL;
#pragma unroll 4
  for (int t2 = 0; t2 < 64; ++t2) {
    float4 cc = corn[t2];                           // broadcast — conflict-free
    float aj  = car[t2];
    float iw = fminf(bx2, cc.z) - fmaxf(bx1, cc.x); iw = fmaxf(iw, 0.0f);
    float ih = fminf(by2, cc.w) - fmaxf(by1, cc.y); ih = fmaxf(ih, 0.0f);
    float inter = iw * ih;
    float iou = inter / (areai + aj - inter + 1e-12f);
    if ((iou > NMS_TH) & (t2 > jmin)) bits |= 1ULL << t2;
  }

  supmatT[((size_t)b * SWRD + colg) * NROW + row] = bits;   // coalesced
  if (bits && colg > rowg)
    atomicOr(&rowmask[(size_t)b * NROW + row], 1ULL << colg);
}

// ------------------------------------------------------------------ scan ----
// Greedy NMS over precomputed bitmasks. One wave per batch; 53 chunk steps.
// All per-chunk state (diag words, rowmask) prefetched into LDS up front so
// the serial loop touches global memory only for sparse propagate rows.
__global__ __launch_bounds__(64) void k_scan(const unsigned long long* __restrict__ supmatT,
                                             const unsigned long long* __restrict__ rowmask,
                                             const unsigned long long* __restrict__ posm,
                                             const float* __restrict__ sScore,
                                             const int* __restrict__ sIdx,
                                             float* __restrict__ out) {
  int b = blockIdx.x;
  int l = threadIdx.x;            // 0..63
  __shared__ unsigned long long remv[SWRD];
  __shared__ unsigned long long diagS[SWRD * 64];   // 27 KB
  __shared__ unsigned long long rmS[NROW];          // 27 KB

  const unsigned long long* smT = supmatT + (size_t)b * SWRD * NROW;
  const unsigned long long* rmB = rowmask + (size_t)b * NROW;

  if (l < SWRD) remv[l] = ~posm[b * NWRD + l];      // bit set = suppressed/invalid

  // prefetch diagonal words: diagS[c*64+r] = smT[c][c*64+r] — 53 coalesced loads
#pragma unroll 4
  for (int i = l; i < SWRD * 64; i += 64) {
    int c = i >> 6;
    diagS[i] = smT[(size_t)c * NROW + i];           // c*NROW + c*64 + r == c*NROW + i? no:
  }
  // NOTE: smT row index for diag word c, lane r is (c*64 + r); the word index is c.
  // Correct address: smT[c*NROW + c*64 + r]. Fix-up loop above would be wrong, so
  // overwrite with the correct values (still 53 coalesced loads, compiler merges).
#pragma unroll 4
  for (int i = l; i < SWRD * 64; i += 64) {
    int c = i >> 6;
    int r = i & 63;
    diagS[i] = smT[(size_t)c * NROW + (c << 6) + r];
  }
#pragma unroll 4
  for (int i = l; i < NROW; i += 64) rmS[i] = rmB[i];
  __syncthreads();

  for (int c = 0; c < SWRD; ++c) {
    int row = (c << 6) + l;
    unsigned long long diag = diagS[(c << 6) + l];  // LDS, 2-way aliasing (free)
    unsigned long long rm   = rmS[row];             // LDS
    unsigned long long cur  = remv[c];              // broadcast

    // intra-chunk greedy resolve — walk only lanes with nonzero diag, ascending
    unsigned long long m = __ballot(diag != 0ULL);
    while (m) {
      int k = __ffsll((long long)m) - 1;
      m &= m - 1;
      unsigned long long dk = __shfl(diag, k);
      if (!((cur >> k) & 1ULL)) cur |= dk;
    }
    if (l == 0) remv[c] = cur;

    // propagate kept rows' suppression bits to later words (sparse, global)
    unsigned long long above = (rm >> (c + 1)) << (c + 1);
    bool act = (!((cur >> l) & 1ULL)) && (above != 0ULL);
    if (act) {
      unsigned long long mm = above;
      while (mm) {
        int w = __ffsll((long long)mm) - 1;
        mm &= mm - 1;
        atomicOr(&remv[w], smT[(size_t)w * NROW + row]);
      }
    }
    __syncthreads();
  }

  // kept set == bits still clear
  for (int c = 0; c < SWRD; ++c) {
    int p = (c << 6) + l;
    if (p < NBOX && !((remv[c] >> l) & 1ULL)) {
      int oi  = sIdx[b * NPAD + p];
      float s = sScore[b * NPAD + p];
      out[((size_t)b * NBOX + oi) * PROBC + NCLS] = s;
    }
  }
}

// ---------------------------------------------------------------- launch ----
extern "C" void kernel_launch(void* const* d_in, const int* in_sizes, int n_in,
                              void* d_out, int out_size, void* d_ws, size_t ws_size,
                              hipStream_t stream) {
  const float* x  = (const float*)d_in[0];
  const float* im = (const float*)d_in[1];
  float* out = (float*)d_out;

  float* scores = (float*)d_ws;                                   // NB*NBOX
  float* sScore = scores + (size_t)NB * NBOX;                     // NB*NPAD
  int*   sIdx   = (int*)(sScore + (size_t)NB * NPAD);             // NB*NPAD
  float4* sBox  = (float4*)(sIdx + (size_t)NB * NPAD);            // NB*NPAD (16B-aligned)
  unsigned long long* posm    = (unsigned long long*)(sBox + (size_t)NB * NPAD); // NB*NWRD
  unsigned long long* supmatT = posm + (size_t)NB * NWRD;         // NB*SWRD*NROW
  unsigned long long* rowmask = supmatT + (size_t)NB * SWRD * NROW; // NB*NROW

  hipLaunchKernelGGL(k_decode, dim3((NB * NBOX + 255) / 256), dim3(256), 0, stream,
                     x, im, out, scores);
  hipLaunchKernelGGL(k_sort, dim3(NB), dim3(1024), 0, stream,
                     scores, out, sScore, sIdx, sBox, posm, rowmask);
  hipLaunchKernelGGL(k_supmat, dim3(SWRD, SWRD, NB), dim3(64), 0, stream,
                     sBox, supmatT, rowmask);
  hipLaunchKernelGGL(k_scan, dim3(NB), dim3(64), 0, stream,
                     supmatT, rowmask, posm, sScore, sIdx, out);
}

// Round 5
// 307.722 us; speedup vs baseline: 4.9229x; 1.1847x over previous
//
#include <hip/hip_runtime.h>
#include <stdint.h>

#pragma clang fp contract(off)

#define NCLS   20
#define NA     5
#define NB     16
#define Hg     26
#define Wg     26
#define HWc    (Hg*Wg)            // 676
#define NBOX   (NA*HWc)           // 3380
#define NPAD   4096
#define NWRD   (NPAD/64)          // 64
#define NROW   3392               // 53*64, padded row count
#define SWRD   53                 // words covering 3380 boxes
#define PROBC  (NCLS+1)           // 21
#define PRE_TH 0.005f
#define NMS_TH 0.45f

__constant__ float c_bias[10] = {1.08f,1.19f,3.42f,4.41f,6.63f,11.38f,9.42f,5.11f,16.62f,10.52f};

// ---------------------------------------------------------------- decode ----
__global__ __launch_bounds__(256) void k_decode(const float* __restrict__ x,
                                                const float* __restrict__ im_info,
                                                float* __restrict__ out,
                                                float* __restrict__ scores) {
  int t = blockIdx.x * 256 + threadIdx.x;
  if (t >= NB * NBOX) return;
  int b  = t / NBOX;
  int n  = t - b * NBOX;
  int a  = n / HWc;
  int hw = n - a * HWc;
  int h  = hw / Wg;
  int w  = hw - h * Wg;

  const float* xb = x + (size_t)b * 125 * HWc;
  float tx = xb[(2*a  ) * HWc + hw];
  float ty = xb[(2*a+1) * HWc + hw];
  float tw = xb[(10+2*a) * HWc + hw];
  float th = xb[(11+2*a) * HWc + hw];
  float to = xb[(20+a  ) * HWc + hw];

  float sx  = 1.0f / (1.0f + expf(-tx));
  float sy  = 1.0f / (1.0f + expf(-ty));
  float obj = 1.0f / (1.0f + expf(-to));

  float cf[NCLS];
  float mx = -3.402823e38f;
#pragma unroll
  for (int c = 0; c < NCLS; ++c) {
    cf[c] = xb[(25 + c*NA + a) * HWc + hw];
    mx = fmaxf(mx, cf[c]);
  }
  float sum = 0.f;
#pragma unroll
  for (int c = 0; c < NCLS; ++c) { cf[c] = expf(cf[c] - mx); sum += cf[c]; }

  float* op = out + ((size_t)b * NBOX + n) * PROBC;
#pragma unroll
  for (int c = 0; c < NCLS; ++c) op[c] = cf[c] / sum * obj;
  op[NCLS] = 0.f;   // obj channel; scan kernel writes kept scores later

  // box decode — replicate reference op order exactly
  float Wf = (float)Wg, Hf = (float)Hg;
  float bx = ((float)w + sx) / Wf;
  float by = ((float)h + sy) / Hf;
  float bw = c_bias[2*a]   * expf(tw) / Wf;
  float bh = c_bias[2*a+1] * expf(th) / Hf;
  float netw = Wf * 32.0f;
  float neth = Hf * 32.0f;
  float imh = im_info[0], imw = im_info[1];
  bool cond   = (netw / imw) < (neth / imh);
  float new_w = cond ? netw : (imw * neth / imh);
  float new_h = cond ? (imh * netw / imw) : neth;
  bx = (bx - (netw - new_w) * 0.5f / netw) / (new_w / netw);
  by = (by - (neth - new_h) * 0.5f / neth) / (new_h / neth);
  bw = bw * (netw / new_w);
  bh = bh * (neth / new_h);
  float X  = bx * imw, Y = by * imh, Wd = bw * imw, Hd = bh * imh;

  float* ob = out + (size_t)NB * NBOX * PROBC + ((size_t)b * NBOX + n) * 4;
  ob[0] = X; ob[1] = Y; ob[2] = Wd; ob[3] = Hd;

  scores[t] = (obj < PRE_TH) ? 0.f : obj;
}

// ------------------------------------------------------------------ sort ----
// key = (score_bits << 32) | (0xFFFFFFFF - idx): descending sort == stable argsort(-s)
__global__ __launch_bounds__(1024) void k_sort(const float* __restrict__ scores,
                                               const float* __restrict__ out,   // bbox region read
                                               float* __restrict__ sScore,
                                               int* __restrict__ sIdx,
                                               float4* __restrict__ sBox,
                                               unsigned long long* __restrict__ posm) {
  int b = blockIdx.x;
  __shared__ unsigned long long key[NPAD];

  for (int i = threadIdx.x; i < NPAD; i += 1024) {
    unsigned long long k = 0ULL;
    if (i < NBOX) {
      float s = scores[b * NBOX + i];
      unsigned int bits = __float_as_uint(s);       // s >= 0 -> monotone bits
      k = ((unsigned long long)bits << 32) | (unsigned long long)(0xFFFFFFFFu - (unsigned)i);
    }
    key[i] = k;
  }
  __syncthreads();

  for (int k = 2; k <= NPAD; k <<= 1) {
    for (int j = k >> 1; j > 0; j >>= 1) {
      for (int i = threadIdx.x; i < NPAD; i += 1024) {
        int ixj = i ^ j;
        if (ixj > i) {
          bool desc = ((i & k) == 0);
          unsigned long long a = key[i], c = key[ixj];
          bool sw = desc ? (a < c) : (a > c);
          if (sw) { key[i] = c; key[ixj] = a; }
        }
      }
      __syncthreads();
    }
  }

  const float4* outBox = (const float4*)(out + (size_t)NB * NBOX * PROBC);
  for (int i = threadIdx.x; i < NPAD; i += 1024) {
    unsigned long long k = key[i];
    float s = __uint_as_float((unsigned)(k >> 32));
    bool pos = (k >> 32) != 0ULL;                   // s > 0
    unsigned long long bal = __ballot(pos);
    if ((threadIdx.x & 63) == 0) posm[b * NWRD + (i >> 6)] = bal;
    sScore[b * NPAD + i] = s;
    int oi = (int)(0xFFFFFFFFu - (unsigned)(k & 0xFFFFFFFFu));
    sIdx[b * NPAD + i] = oi;
    float4 bx = make_float4(0.f, 0.f, 0.f, 0.f);
    if (oi >= 0 && oi < NBOX) bx = outBox[(size_t)b * NBOX + oi];
    sBox[b * NPAD + i] = bx;
  }
}

// ---------------------------------------------------------------- supmat ----
// One thread per ROW, inner loop over the col-block's 64 boxes staged in LDS
// (broadcast reads, conflict-free). Transposed layout supmatT[b][w][row]:
// coalesced stores; contiguous per-word rows make the scan's pull coalesced.
__global__ __launch_bounds__(64) void k_supmat(const float4* __restrict__ sBox,
                                               unsigned long long* __restrict__ supmatT) {
  int colg = blockIdx.x;
  int rowg = blockIdx.y;
  if (colg < rowg) return;                          // strictly-lower blocks never read
  int b = blockIdx.z;
  int l = threadIdx.x;                              // 0..63

  __shared__ float4 corn[64];                       // col corners x1,y1,x2,y2
  __shared__ float  car[64];                        // col areas

  float4 cb = sBox[(size_t)b * NPAD + colg * 64 + l];
  float c1 = cb.x - cb.z * 0.5f;
  float d1 = cb.y - cb.w * 0.5f;
  float c2 = cb.x + cb.z * 0.5f;
  float d2 = cb.y + cb.w * 0.5f;
  corn[l] = make_float4(c1, d1, c2, d2);
  car[l]  = (c2 - c1) * (d2 - d1);
  __syncthreads();

  int row = rowg * 64 + l;
  float4 rb = sBox[(size_t)b * NPAD + row];
  float bx1 = rb.x - rb.z * 0.5f;
  float by1 = rb.y - rb.w * 0.5f;
  float bx2 = rb.x + rb.z * 0.5f;
  float by2 = rb.y + rb.w * 0.5f;
  float areai = (bx2 - bx1) * (by2 - by1);

  int jmin = row - colg * 64;                       // bits t2 > jmin are j > row
  unsigned long long bits = 0ULL;
#pragma unroll 4
  for (int t2 = 0; t2 < 64; ++t2) {
    float4 cc = corn[t2];                           // broadcast — conflict-free
    float aj  = car[t2];
    float iw = fminf(bx2, cc.z) - fmaxf(bx1, cc.x); iw = fmaxf(iw, 0.0f);
    float ih = fminf(by2, cc.w) - fmaxf(by1, cc.y); ih = fmaxf(ih, 0.0f);
    float inter = iw * ih;
    float iou = inter / (areai + aj - inter + 1e-12f);
    if ((iou > NMS_TH) & (t2 > jmin)) bits |= 1ULL << t2;
  }

  supmatT[((size_t)b * SWRD + colg) * NROW + row] = bits;   // coalesced
}

// ------------------------------------------------------------------ scan ----
// Greedy NMS, pull model. One 512-thread block per batch; 53 chunk steps.
// Chunk c: remv[c] |= OR over kept rows r < c*64 of smT[c][r] (coalesced
// strided load + OR-reduce across 8 waves), then wave 0 resolves the 64
// intra-chunk boxes from the prefetched diagonal words.
__global__ __launch_bounds__(512) void k_scan(const unsigned long long* __restrict__ supmatT,
                                              const unsigned long long* __restrict__ posm,
                                              const float* __restrict__ sScore,
                                              const int* __restrict__ sIdx,
                                              float* __restrict__ out) {
  int b    = blockIdx.x;
  int tid  = threadIdx.x;
  int lane = tid & 63;
  int wid  = tid >> 6;                              // 0..7
  __shared__ unsigned long long remv[SWRD];
  __shared__ unsigned long long diagS[SWRD * 64];   // 27 KB
  __shared__ unsigned long long parts[8];

  const unsigned long long* smT = supmatT + (size_t)b * SWRD * NROW;

  if (tid < SWRD) remv[tid] = ~posm[b * NWRD + tid];  // bit set = suppressed/invalid

  // prefetch diagonal words: diagS[c*64+r] = smT[c][c*64+r]
  for (int i = tid; i < SWRD * 64; i += 512) {
    int c = i >> 6;
    int r = i & 63;
    diagS[i] = smT[(size_t)c * NROW + (c << 6) + r];
  }
  __syncthreads();

  for (int c = 0; c < SWRD; ++c) {
    // ---- pull: OR suppression words from kept earlier rows (coalesced) ----
    unsigned long long acc = 0ULL;
    int lim = c << 6;
    for (int idx = tid; idx < lim; idx += 512) {
      unsigned long long rv = remv[idx >> 6];       // LDS broadcast per wave-group
      if (!((rv >> (idx & 63)) & 1ULL))
        acc |= smT[(size_t)c * NROW + idx];
    }
#pragma unroll
    for (int off = 32; off >= 1; off >>= 1) acc |= __shfl_xor(acc, off);
    if (lane == 0) parts[wid] = acc;
    __syncthreads();

    // ---- resolve: wave 0 only ----
    if (wid == 0) {
      unsigned long long cur = remv[c];
#pragma unroll
      for (int p = 0; p < 8; ++p) cur |= parts[p];
      unsigned long long diag = diagS[(c << 6) + lane];
      unsigned long long m = __ballot(diag != 0ULL);
      while (m) {
        int k = __ffsll((long long)m) - 1;
        m &= m - 1;
        unsigned long long dk = __shfl(diag, k);
        if (!((cur >> k) & 1ULL)) cur |= dk;
      }
      if (lane == 0) remv[c] = cur;
    }
    __syncthreads();
  }

  // kept set == bits still clear
  for (int p = tid; p < NBOX; p += 512) {
    if (!((remv[p >> 6] >> (p & 63)) & 1ULL)) {
      int oi  = sIdx[b * NPAD + p];
      float s = sScore[b * NPAD + p];
      out[((size_t)b * NBOX + oi) * PROBC + NCLS] = s;
    }
  }
}

// ---------------------------------------------------------------- launch ----
extern "C" void kernel_launch(void* const* d_in, const int* in_sizes, int n_in,
                              void* d_out, int out_size, void* d_ws, size_t ws_size,
                              hipStream_t stream) {
  const float* x  = (const float*)d_in[0];
  const float* im = (const float*)d_in[1];
  float* out = (float*)d_out;

  float* scores = (float*)d_ws;                                   // NB*NBOX
  float* sScore = scores + (size_t)NB * NBOX;                     // NB*NPAD
  int*   sIdx   = (int*)(sScore + (size_t)NB * NPAD);             // NB*NPAD
  float4* sBox  = (float4*)(sIdx + (size_t)NB * NPAD);            // NB*NPAD (16B-aligned)
  unsigned long long* posm    = (unsigned long long*)(sBox + (size_t)NB * NPAD); // NB*NWRD
  unsigned long long* supmatT = posm + (size_t)NB * NWRD;         // NB*SWRD*NROW

  hipLaunchKernelGGL(k_decode, dim3((NB * NBOX + 255) / 256), dim3(256), 0, stream,
                     x, im, out, scores);
  hipLaunchKernelGGL(k_sort, dim3(NB), dim3(1024), 0, stream,
                     scores, out, sScore, sIdx, sBox, posm);
  hipLaunchKernelGGL(k_supmat, dim3(SWRD, SWRD, NB), dim3(64), 0, stream,
                     sBox, supmatT);
  hipLaunchKernelGGL(k_scan, dim3(NB), dim3(512), 0, stream,
                     supmatT, posm, sScore, sIdx, out);
}

// Round 6
// 298.814 us; speedup vs baseline: 5.0697x; 1.0298x over previous
//
#include <hip/hip_runtime.h>
#include <stdint.h>

#pragma clang fp contract(off)

#define NCLS   20
#define NA     5
#define NB     16
#define Hg     26
#define Wg     26
#define HWc    (Hg*Wg)            // 676
#define NBOX   (NA*HWc)           // 3380
#define NPAD   4096
#define NWRD   (NPAD/64)          // 64
#define NROW   3392               // 53*64, padded row count
#define SWRD   53                 // words covering 3380 boxes
#define PROBC  (NCLS+1)           // 21
#define PRE_TH 0.005f
#define NMS_TH 0.45f
#define ECAP   2048               // LDS entry-cache capacity
#define ETOT   88192              // 32*53*52: worst-case entries per batch
#define SEGB(c) (32*(c)*((c)-1))  // segment base for chunk c (capacity c*64)

__constant__ float c_bias[10] = {1.08f,1.19f,3.42f,4.41f,6.63f,11.38f,9.42f,5.11f,16.62f,10.52f};

// ---------------------------------------------------------------- decode ----
__global__ __launch_bounds__(256) void k_decode(const float* __restrict__ x,
                                                const float* __restrict__ im_info,
                                                float* __restrict__ out,
                                                float* __restrict__ scores) {
  int t = blockIdx.x * 256 + threadIdx.x;
  if (t >= NB * NBOX) return;
  int b  = t / NBOX;
  int n  = t - b * NBOX;
  int a  = n / HWc;
  int hw = n - a * HWc;
  int h  = hw / Wg;
  int w  = hw - h * Wg;

  const float* xb = x + (size_t)b * 125 * HWc;
  float tx = xb[(2*a  ) * HWc + hw];
  float ty = xb[(2*a+1) * HWc + hw];
  float tw = xb[(10+2*a) * HWc + hw];
  float th = xb[(11+2*a) * HWc + hw];
  float to = xb[(20+a  ) * HWc + hw];

  float sx  = 1.0f / (1.0f + expf(-tx));
  float sy  = 1.0f / (1.0f + expf(-ty));
  float obj = 1.0f / (1.0f + expf(-to));

  float cf[NCLS];
  float mx = -3.402823e38f;
#pragma unroll
  for (int c = 0; c < NCLS; ++c) {
    cf[c] = xb[(25 + c*NA + a) * HWc + hw];
    mx = fmaxf(mx, cf[c]);
  }
  float sum = 0.f;
#pragma unroll
  for (int c = 0; c < NCLS; ++c) { cf[c] = expf(cf[c] - mx); sum += cf[c]; }

  float* op = out + ((size_t)b * NBOX + n) * PROBC;
#pragma unroll
  for (int c = 0; c < NCLS; ++c) op[c] = cf[c] / sum * obj;
  op[NCLS] = 0.f;   // obj channel; scan kernel writes kept scores later

  // box decode — replicate reference op order exactly
  float Wf = (float)Wg, Hf = (float)Hg;
  float bx = ((float)w + sx) / Wf;
  float by = ((float)h + sy) / Hf;
  float bw = c_bias[2*a]   * expf(tw) / Wf;
  float bh = c_bias[2*a+1] * expf(th) / Hf;
  float netw = Wf * 32.0f;
  float neth = Hf * 32.0f;
  float imh = im_info[0], imw = im_info[1];
  bool cond   = (netw / imw) < (neth / imh);
  float new_w = cond ? netw : (imw * neth / imh);
  float new_h = cond ? (imh * netw / imw) : neth;
  bx = (bx - (netw - new_w) * 0.5f / netw) / (new_w / netw);
  by = (by - (neth - new_h) * 0.5f / neth) / (new_h / neth);
  bw = bw * (netw / new_w);
  bh = bh * (neth / new_h);
  float X  = bx * imw, Y = by * imh, Wd = bw * imw, Hd = bh * imh;

  float* ob = out + (size_t)NB * NBOX * PROBC + ((size_t)b * NBOX + n) * 4;
  ob[0] = X; ob[1] = Y; ob[2] = Wd; ob[3] = Hd;

  scores[t] = (obj < PRE_TH) ? 0.f : obj;
}

// ------------------------------------------------------------------ sort ----
// key = (score_bits << 32) | (0xFFFFFFFF - idx): descending sort == stable argsort(-s)
// Also zeroes per-chunk entry counters (runs before k_supmat — stream order).
__global__ __launch_bounds__(1024) void k_sort(const float* __restrict__ scores,
                                               const float* __restrict__ out,   // bbox region read
                                               float* __restrict__ sScore,
                                               int* __restrict__ sIdx,
                                               float4* __restrict__ sBox,
                                               unsigned long long* __restrict__ posm,
                                               int* __restrict__ cnt) {
  int b = blockIdx.x;
  __shared__ unsigned long long key[NPAD];

  if (threadIdx.x < SWRD) cnt[b * SWRD + threadIdx.x] = 0;

  for (int i = threadIdx.x; i < NPAD; i += 1024) {
    unsigned long long k = 0ULL;
    if (i < NBOX) {
      float s = scores[b * NBOX + i];
      unsigned int bits = __float_as_uint(s);       // s >= 0 -> monotone bits
      k = ((unsigned long long)bits << 32) | (unsigned long long)(0xFFFFFFFFu - (unsigned)i);
    }
    key[i] = k;
  }
  __syncthreads();

  for (int k = 2; k <= NPAD; k <<= 1) {
    for (int j = k >> 1; j > 0; j >>= 1) {
      for (int i = threadIdx.x; i < NPAD; i += 1024) {
        int ixj = i ^ j;
        if (ixj > i) {
          bool desc = ((i & k) == 0);
          unsigned long long a = key[i], c = key[ixj];
          bool sw = desc ? (a < c) : (a > c);
          if (sw) { key[i] = c; key[ixj] = a; }
        }
      }
      __syncthreads();
    }
  }

  const float4* outBox = (const float4*)(out + (size_t)NB * NBOX * PROBC);
  for (int i = threadIdx.x; i < NPAD; i += 1024) {
    unsigned long long k = key[i];
    float s = __uint_as_float((unsigned)(k >> 32));
    bool pos = (k >> 32) != 0ULL;                   // s > 0
    unsigned long long bal = __ballot(pos);
    if ((threadIdx.x & 63) == 0) posm[b * NWRD + (i >> 6)] = bal;
    sScore[b * NPAD + i] = s;
    int oi = (int)(0xFFFFFFFFu - (unsigned)(k & 0xFFFFFFFFu));
    sIdx[b * NPAD + i] = oi;
    float4 bx = make_float4(0.f, 0.f, 0.f, 0.f);
    if (oi >= 0 && oi < NBOX) bx = outBox[(size_t)b * NBOX + oi];
    sBox[b * NPAD + i] = bx;
  }
}

// ---------------------------------------------------------------- supmat ----
// One thread per ROW; col-block's 64 boxes staged in LDS (broadcast reads,
// conflict-free). Diagonal words -> dense diag[b][c][64]; nonzero off-diagonal
// words appended as sparse (row, bits) entries per (b, colg) segment.
__global__ __launch_bounds__(64) void k_supmat(const float4* __restrict__ sBox,
                                               unsigned long long* __restrict__ diag,
                                               ulonglong2* __restrict__ entries,
                                               int* __restrict__ cnt) {
  int colg = blockIdx.x;
  int rowg = blockIdx.y;
  if (colg < rowg) return;                          // strictly-lower blocks never read
  int b = blockIdx.z;
  int l = threadIdx.x;                              // 0..63

  __shared__ float4 corn[64];                       // col corners x1,y1,x2,y2
  __shared__ float  car[64];                        // col areas

  float4 cb = sBox[(size_t)b * NPAD + colg * 64 + l];
  float c1 = cb.x - cb.z * 0.5f;
  float d1 = cb.y - cb.w * 0.5f;
  float c2 = cb.x + cb.z * 0.5f;
  float d2 = cb.y + cb.w * 0.5f;
  corn[l] = make_float4(c1, d1, c2, d2);
  car[l]  = (c2 - c1) * (d2 - d1);
  __syncthreads();

  int row = rowg * 64 + l;
  float4 rb = sBox[(size_t)b * NPAD + row];
  float bx1 = rb.x - rb.z * 0.5f;
  float by1 = rb.y - rb.w * 0.5f;
  float bx2 = rb.x + rb.z * 0.5f;
  float by2 = rb.y + rb.w * 0.5f;
  float areai = (bx2 - bx1) * (by2 - by1);

  int jmin = row - colg * 64;                       // bits t2 > jmin are j > row
  unsigned long long bits = 0ULL;
#pragma unroll 4
  for (int t2 = 0; t2 < 64; ++t2) {
    float4 cc = corn[t2];                           // broadcast — conflict-free
    float aj  = car[t2];
    float iw = fminf(bx2, cc.z) - fmaxf(bx1, cc.x); iw = fmaxf(iw, 0.0f);
    float ih = fminf(by2, cc.w) - fmaxf(by1, cc.y); ih = fmaxf(ih, 0.0f);
    float inter = iw * ih;
    float iou = inter / (areai + aj - inter + 1e-12f);
    if ((iou > NMS_TH) & (t2 > jmin)) bits |= 1ULL << t2;
  }

  if (colg == rowg) {
    diag[((size_t)b * SWRD + colg) * 64 + l] = bits;
  } else if (bits) {
    int p = atomicAdd(&cnt[b * SWRD + colg], 1);    // order-free: OR is commutative
    entries[(size_t)b * ETOT + SEGB(colg) + p] =
        ulonglong2{(unsigned long long)row, bits};
  }
}

// ------------------------------------------------------------------ scan ----
// Greedy NMS over sparse suppression lists. One block per batch; after the
// prefetch, the 53-chunk serial loop runs on wave 0 only, entirely in LDS,
// with no block barriers. Global fallback path covers entry-cache overflow.
__global__ __launch_bounds__(512) void k_scan(const unsigned long long* __restrict__ diag,
                                              const ulonglong2* __restrict__ entries,
                                              const int* __restrict__ cnt,
                                              const unsigned long long* __restrict__ posm,
                                              const float* __restrict__ sScore,
                                              const int* __restrict__ sIdx,
                                              float* __restrict__ out) {
  int b    = blockIdx.x;
  int tid  = threadIdx.x;
  int lane = tid & 63;
  int wid  = tid >> 6;
  __shared__ unsigned long long diagS[SWRD * 64];   // 27 KB
  __shared__ ulonglong2 eLds[ECAP];                 // 32 KB
  __shared__ unsigned long long remv[SWRD];
  __shared__ int offs[SWRD + 1];

  const ulonglong2* segB = entries + (size_t)b * ETOT;

  if (tid < SWRD) remv[tid] = ~posm[b * NWRD + tid];  // bit set = suppressed/invalid
  for (int i = tid; i < SWRD * 64; i += 512)
    diagS[i] = diag[(size_t)b * SWRD * 64 + i];

  if (wid == 0) {                                   // prefix-sum the 53 counts
    int v = (lane < SWRD) ? cnt[b * SWRD + lane] : 0;
    int s = v;
#pragma unroll
    for (int d = 1; d < 64; d <<= 1) {
      int o = __shfl_up(s, d);
      if (lane >= d) s += o;
    }
    if (lane < SWRD) offs[lane + 1] = s;
    if (lane == 0)  offs[0] = 0;
  }
  __syncthreads();

  int total = offs[SWRD];
  bool inLds = (total <= ECAP);
  if (inLds) {
    for (int g = tid; g < total; g += 512) {
      int lo = 0, hi = SWRD;                        // find c: offs[c] <= g < offs[c+1]
      while (hi - lo > 1) { int mid = (lo + hi) >> 1; if (offs[mid] <= g) lo = mid; else hi = mid; }
      eLds[g] = segB[SEGB(lo) + (g - offs[lo])];
    }
  }
  __syncthreads();

  if (wid == 0) {
    for (int c = 0; c < SWRD; ++c) {
      unsigned long long acc = 0ULL;
      int e0 = offs[c], e1 = offs[c + 1];
      if (inLds) {
        for (int g = e0 + lane; g < e1; g += 64) {
          ulonglong2 ent = eLds[g];
          int row = (int)ent.x;
          if (!((remv[row >> 6] >> (row & 63)) & 1ULL)) acc |= ent.y;
        }
      } else {
        for (int g = e0 + lane; g < e1; g += 64) {
          ulonglong2 ent = segB[SEGB(c) + (g - e0)];
          int row = (int)ent.x;
          if (!((remv[row >> 6] >> (row & 63)) & 1ULL)) acc |= ent.y;
        }
      }
#pragma unroll
      for (int off = 32; off >= 1; off >>= 1) acc |= __shfl_xor(acc, off);

      unsigned long long cur = remv[c] | acc;       // uniform across lanes
      unsigned long long dg  = diagS[(c << 6) + lane];
      unsigned long long m   = __ballot(dg != 0ULL);
      while (m) {
        int k = __ffsll((long long)m) - 1;
        m &= m - 1;
        unsigned long long dk = __shfl(dg, k);
        if (!((cur >> k) & 1ULL)) cur |= dk;
      }
      if (lane == 0) remv[c] = cur;
    }
  }
  __syncthreads();

  // kept set == bits still clear
  for (int p = tid; p < NBOX; p += 512) {
    if (!((remv[p >> 6] >> (p & 63)) & 1ULL)) {
      int oi  = sIdx[b * NPAD + p];
      float s = sScore[b * NPAD + p];
      out[((size_t)b * NBOX + oi) * PROBC + NCLS] = s;
    }
  }
}

// ---------------------------------------------------------------- launch ----
extern "C" void kernel_launch(void* const* d_in, const int* in_sizes, int n_in,
                              void* d_out, int out_size, void* d_ws, size_t ws_size,
                              hipStream_t stream) {
  const float* x  = (const float*)d_in[0];
  const float* im = (const float*)d_in[1];
  float* out = (float*)d_out;

  float* scores = (float*)d_ws;                                   // NB*NBOX
  float* sScore = scores + (size_t)NB * NBOX;                     // NB*NPAD
  int*   sIdx   = (int*)(sScore + (size_t)NB * NPAD);             // NB*NPAD
  float4* sBox  = (float4*)(sIdx + (size_t)NB * NPAD);            // NB*NPAD (16B-aligned)
  unsigned long long* posm = (unsigned long long*)(sBox + (size_t)NB * NPAD); // NB*NWRD
  unsigned long long* diag = posm + (size_t)NB * NWRD;            // NB*SWRD*64
  int* cnt = (int*)(diag + (size_t)NB * SWRD * 64);               // NB*SWRD
  // pad cnt region to 16B alignment for ulonglong2 entries
  ulonglong2* entries = (ulonglong2*)((char*)cnt + (((size_t)NB * SWRD * 4 + 15) & ~(size_t)15)); // NB*ETOT

  hipLaunchKernelGGL(k_decode, dim3((NB * NBOX + 255) / 256), dim3(256), 0, stream,
                     x, im, out, scores);
  hipLaunchKernelGGL(k_sort, dim3(NB), dim3(1024), 0, stream,
                     scores, out, sScore, sIdx, sBox, posm, cnt);
  hipLaunchKernelGGL(k_supmat, dim3(SWRD, SWRD, NB), dim3(64), 0, stream,
                     sBox, diag, entries, cnt);
  hipLaunchKernelGGL(k_scan, dim3(NB), dim3(512), 0, stream,
                     diag, entries, cnt, posm, sScore, sIdx, out);
}

// Round 7
// 259.415 us; speedup vs baseline: 5.8397x; 1.1519x over previous
//
#include <hip/hip_runtime.h>
#include <stdint.h>

#pragma clang fp contract(off)

#define NCLS   20
#define NA     5
#define NB     16
#define Hg     26
#define Wg     26
#define HWc    (Hg*Wg)            // 676
#define NBOX   (NA*HWc)           // 3380
#define NPAD   4096
#define NWRD   (NPAD/64)          // 64
#define NROW   3392               // 53*64, padded row count
#define SWRD   53                 // words covering 3380 boxes
#define PROBC  (NCLS+1)           // 21
#define PRE_TH 0.005f
#define NMS_TH 0.45f
#define ECHUNK 1024               // LDS entries per ping-pong buffer
#define ETOT   88192              // 32*53*52: worst-case entries per batch
#define SEGB(c) (32*(c)*((c)-1))  // segment base for chunk c (capacity c*64)

__constant__ float c_bias[10] = {1.08f,1.19f,3.42f,4.41f,6.63f,11.38f,9.42f,5.11f,16.62f,10.52f};

// ---------------------------------------------------------------- decode ----
__global__ __launch_bounds__(256) void k_decode(const float* __restrict__ x,
                                                const float* __restrict__ im_info,
                                                float* __restrict__ out,
                                                float* __restrict__ scores) {
  int t = blockIdx.x * 256 + threadIdx.x;
  if (t >= NB * NBOX) return;
  int b  = t / NBOX;
  int n  = t - b * NBOX;
  int a  = n / HWc;
  int hw = n - a * HWc;
  int h  = hw / Wg;
  int w  = hw - h * Wg;

  const float* xb = x + (size_t)b * 125 * HWc;
  float tx = xb[(2*a  ) * HWc + hw];
  float ty = xb[(2*a+1) * HWc + hw];
  float tw = xb[(10+2*a) * HWc + hw];
  float th = xb[(11+2*a) * HWc + hw];
  float to = xb[(20+a  ) * HWc + hw];

  float sx  = 1.0f / (1.0f + expf(-tx));
  float sy  = 1.0f / (1.0f + expf(-ty));
  float obj = 1.0f / (1.0f + expf(-to));

  float cf[NCLS];
  float mx = -3.402823e38f;
#pragma unroll
  for (int c = 0; c < NCLS; ++c) {
    cf[c] = xb[(25 + c*NA + a) * HWc + hw];
    mx = fmaxf(mx, cf[c]);
  }
  float sum = 0.f;
#pragma unroll
  for (int c = 0; c < NCLS; ++c) { cf[c] = expf(cf[c] - mx); sum += cf[c]; }

  float* op = out + ((size_t)b * NBOX + n) * PROBC;
#pragma unroll
  for (int c = 0; c < NCLS; ++c) op[c] = cf[c] / sum * obj;
  op[NCLS] = 0.f;   // obj channel; scan kernel writes kept scores later

  // box decode — replicate reference op order exactly
  float Wf = (float)Wg, Hf = (float)Hg;
  float bx = ((float)w + sx) / Wf;
  float by = ((float)h + sy) / Hf;
  float bw = c_bias[2*a]   * expf(tw) / Wf;
  float bh = c_bias[2*a+1] * expf(th) / Hf;
  float netw = Wf * 32.0f;
  float neth = Hf * 32.0f;
  float imh = im_info[0], imw = im_info[1];
  bool cond   = (netw / imw) < (neth / imh);
  float new_w = cond ? netw : (imw * neth / imh);
  float new_h = cond ? (imh * netw / imw) : neth;
  bx = (bx - (netw - new_w) * 0.5f / netw) / (new_w / netw);
  by = (by - (neth - new_h) * 0.5f / neth) / (new_h / neth);
  bw = bw * (netw / new_w);
  bh = bh * (neth / new_h);
  float X  = bx * imw, Y = by * imh, Wd = bw * imw, Hd = bh * imh;

  float* ob = out + (size_t)NB * NBOX * PROBC + ((size_t)b * NBOX + n) * 4;
  ob[0] = X; ob[1] = Y; ob[2] = Wd; ob[3] = Hd;

  scores[t] = (obj < PRE_TH) ? 0.f : obj;
}

// ------------------------------------------------------------------ sort ----
// key = (score_bits << 32) | (0xFFFFFFFF - idx): descending sort == stable argsort(-s)
// Also zeroes per-chunk entry counters (runs before k_supmat — stream order).
__global__ __launch_bounds__(1024) void k_sort(const float* __restrict__ scores,
                                               const float* __restrict__ out,   // bbox region read
                                               float* __restrict__ sScore,
                                               int* __restrict__ sIdx,
                                               float4* __restrict__ sBox,
                                               unsigned long long* __restrict__ posm,
                                               int* __restrict__ cnt) {
  int b = blockIdx.x;
  __shared__ unsigned long long key[NPAD];

  if (threadIdx.x < SWRD) cnt[b * SWRD + threadIdx.x] = 0;

  for (int i = threadIdx.x; i < NPAD; i += 1024) {
    unsigned long long k = 0ULL;
    if (i < NBOX) {
      float s = scores[b * NBOX + i];
      unsigned int bits = __float_as_uint(s);       // s >= 0 -> monotone bits
      k = ((unsigned long long)bits << 32) | (unsigned long long)(0xFFFFFFFFu - (unsigned)i);
    }
    key[i] = k;
  }
  __syncthreads();

  for (int k = 2; k <= NPAD; k <<= 1) {
    for (int j = k >> 1; j > 0; j >>= 1) {
      for (int i = threadIdx.x; i < NPAD; i += 1024) {
        int ixj = i ^ j;
        if (ixj > i) {
          bool desc = ((i & k) == 0);
          unsigned long long a = key[i], c = key[ixj];
          bool sw = desc ? (a < c) : (a > c);
          if (sw) { key[i] = c; key[ixj] = a; }
        }
      }
      __syncthreads();
    }
  }

  const float4* outBox = (const float4*)(out + (size_t)NB * NBOX * PROBC);
  for (int i = threadIdx.x; i < NPAD; i += 1024) {
    unsigned long long k = key[i];
    float s = __uint_as_float((unsigned)(k >> 32));
    bool pos = (k >> 32) != 0ULL;                   // s > 0
    unsigned long long bal = __ballot(pos);
    if ((threadIdx.x & 63) == 0) posm[b * NWRD + (i >> 6)] = bal;
    sScore[b * NPAD + i] = s;
    int oi = (int)(0xFFFFFFFFu - (unsigned)(k & 0xFFFFFFFFu));
    sIdx[b * NPAD + i] = oi;
    float4 bx = make_float4(0.f, 0.f, 0.f, 0.f);
    if (oi >= 0 && oi < NBOX) bx = outBox[(size_t)b * NBOX + oi];
    sBox[b * NPAD + i] = bx;
  }
}

// ---------------------------------------------------------------- supmat ----
// One thread per ROW; col-block's 64 boxes staged in LDS (broadcast reads,
// conflict-free). Diagonal words -> dense diag[b][c][64]; nonzero off-diagonal
// words appended as sparse (row, bits) entries per (b, colg) segment.
__global__ __launch_bounds__(64) void k_supmat(const float4* __restrict__ sBox,
                                               unsigned long long* __restrict__ diag,
                                               ulonglong2* __restrict__ entries,
                                               int* __restrict__ cnt) {
  int colg = blockIdx.x;
  int rowg = blockIdx.y;
  if (colg < rowg) return;                          // strictly-lower blocks never read
  int b = blockIdx.z;
  int l = threadIdx.x;                              // 0..63

  __shared__ float4 corn[64];                       // col corners x1,y1,x2,y2
  __shared__ float  car[64];                        // col areas

  float4 cb = sBox[(size_t)b * NPAD + colg * 64 + l];
  float c1 = cb.x - cb.z * 0.5f;
  float d1 = cb.y - cb.w * 0.5f;
  float c2 = cb.x + cb.z * 0.5f;
  float d2 = cb.y + cb.w * 0.5f;
  corn[l] = make_float4(c1, d1, c2, d2);
  car[l]  = (c2 - c1) * (d2 - d1);
  __syncthreads();

  int row = rowg * 64 + l;
  float4 rb = sBox[(size_t)b * NPAD + row];
  float bx1 = rb.x - rb.z * 0.5f;
  float by1 = rb.y - rb.w * 0.5f;
  float bx2 = rb.x + rb.z * 0.5f;
  float by2 = rb.y + rb.w * 0.5f;
  float areai = (bx2 - bx1) * (by2 - by1);

  int jmin = row - colg * 64;                       // bits t2 > jmin are j > row
  unsigned long long bits = 0ULL;
#pragma unroll 4
  for (int t2 = 0; t2 < 64; ++t2) {
    float4 cc = corn[t2];                           // broadcast — conflict-free
    float aj  = car[t2];
    float iw = fminf(bx2, cc.z) - fmaxf(bx1, cc.x); iw = fmaxf(iw, 0.0f);
    float ih = fminf(by2, cc.w) - fmaxf(by1, cc.y); ih = fmaxf(ih, 0.0f);
    float inter = iw * ih;
    float iou = inter / (areai + aj - inter + 1e-12f);
    if ((iou > NMS_TH) & (t2 > jmin)) bits |= 1ULL << t2;
  }

  if (colg == rowg) {
    diag[((size_t)b * SWRD + colg) * 64 + l] = bits;
  } else if (bits) {
    int p = atomicAdd(&cnt[b * SWRD + colg], 1);    // order-free: OR is commutative
    entries[(size_t)b * ETOT + SEGB(colg) + p] =
        ulonglong2{(unsigned long long)row, bits};
  }
}

// ------------------------------------------------------------------ scan ----
// Greedy NMS over sparse suppression lists, software-pipelined: while wave 0
// resolves chunk c from LDS, waves 1-7 prefetch chunk c+1's entries into the
// other ping-pong buffer. Per-chunk critical path ~= one overlapped HBM trip.
__global__ __launch_bounds__(512) void k_scan(const unsigned long long* __restrict__ diag,
                                              const ulonglong2* __restrict__ entries,
                                              const int* __restrict__ cnt,
                                              const unsigned long long* __restrict__ posm,
                                              const float* __restrict__ sScore,
                                              const int* __restrict__ sIdx,
                                              float* __restrict__ out) {
  int b    = blockIdx.x;
  int tid  = threadIdx.x;
  int lane = tid & 63;
  int wid  = tid >> 6;
  __shared__ unsigned long long diagS[SWRD * 64];   // 27 KB
  __shared__ ulonglong2 ebuf[2][ECHUNK];            // 32 KB ping-pong
  __shared__ unsigned long long remv[SWRD];
  __shared__ int cntS[SWRD];

  const ulonglong2* segB = entries + (size_t)b * ETOT;

  if (tid < SWRD) {
    remv[tid] = ~posm[b * NWRD + tid];              // bit set = suppressed/invalid
    cntS[tid] = cnt[b * SWRD + tid];
  }
  for (int i = tid; i < SWRD * 64; i += 512)
    diagS[i] = diag[(size_t)b * SWRD * 64 + i];
  __syncthreads();
  // note: chunk 0 has zero entries (SEGB(0) capacity 0), so ebuf[0] unused at c=0

  for (int c = 0; c < SWRD; ++c) {
    if (wid > 0) {
      // waves 1-7: prefetch chunk c+1 entries into the other buffer
      if (c + 1 < SWRD) {
        int nn = cntS[c + 1];
        if (nn > ECHUNK) nn = ECHUNK;
        const ulonglong2* sp = segB + SEGB(c + 1);
        for (int g = tid - 64; g < nn; g += 448) ebuf[(c + 1) & 1][g] = sp[g];
      }
    } else {
      // wave 0: masked-OR chunk c's entries (LDS) + overflow tail (global)
      int nc = cntS[c];
      int nl = nc > ECHUNK ? ECHUNK : nc;
      unsigned long long acc = 0ULL;
      for (int g = lane; g < nl; g += 64) {
        ulonglong2 e = ebuf[c & 1][g];
        int row = (int)e.x;
        if (!((remv[row >> 6] >> (row & 63)) & 1ULL)) acc |= e.y;
      }
      for (int g = ECHUNK + lane; g < nc; g += 64) {   // rare overflow path
        ulonglong2 e = segB[SEGB(c) + g];
        int row = (int)e.x;
        if (!((remv[row >> 6] >> (row & 63)) & 1ULL)) acc |= e.y;
      }
#pragma unroll
      for (int off = 32; off >= 1; off >>= 1) acc |= __shfl_xor(acc, off);

      unsigned long long cur = remv[c] | acc;          // uniform across lanes
      unsigned long long dg  = diagS[(c << 6) + lane];
      unsigned long long m   = __ballot(dg != 0ULL);
      while (m) {
        int k = __ffsll((long long)m) - 1;
        m &= m - 1;
        unsigned long long dk = __shfl(dg, k);
        if (!((cur >> k) & 1ULL)) cur |= dk;
      }
      if (lane == 0) remv[c] = cur;
    }
    __syncthreads();
  }

  // kept set == bits still clear
  for (int p = tid; p < NBOX; p += 512) {
    if (!((remv[p >> 6] >> (p & 63)) & 1ULL)) {
      int oi  = sIdx[b * NPAD + p];
      float s = sScore[b * NPAD + p];
      out[((size_t)b * NBOX + oi) * PROBC + NCLS] = s;
    }
  }
}

// ---------------------------------------------------------------- launch ----
extern "C" void kernel_launch(void* const* d_in, const int* in_sizes, int n_in,
                              void* d_out, int out_size, void* d_ws, size_t ws_size,
                              hipStream_t stream) {
  const float* x  = (const float*)d_in[0];
  const float* im = (const float*)d_in[1];
  float* out = (float*)d_out;

  float* scores = (float*)d_ws;                                   // NB*NBOX
  float* sScore = scores + (size_t)NB * NBOX;                     // NB*NPAD
  int*   sIdx   = (int*)(sScore + (size_t)NB * NPAD);             // NB*NPAD
  float4* sBox  = (float4*)(sIdx + (size_t)NB * NPAD);            // NB*NPAD (16B-aligned)
  unsigned long long* posm = (unsigned long long*)(sBox + (size_t)NB * NPAD); // NB*NWRD
  unsigned long long* diag = posm + (size_t)NB * NWRD;            // NB*SWRD*64
  int* cnt = (int*)(diag + (size_t)NB * SWRD * 64);               // NB*SWRD
  // pad cnt region to 16B alignment for ulonglong2 entries
  ulonglong2* entries = (ulonglong2*)((char*)cnt + (((size_t)NB * SWRD * 4 + 15) & ~(size_t)15)); // NB*ETOT

  hipLaunchKernelGGL(k_decode, dim3((NB * NBOX + 255) / 256), dim3(256), 0, stream,
                     x, im, out, scores);
  hipLaunchKernelGGL(k_sort, dim3(NB), dim3(1024), 0, stream,
                     scores, out, sScore, sIdx, sBox, posm, cnt);
  hipLaunchKernelGGL(k_supmat, dim3(SWRD, SWRD, NB), dim3(64), 0, stream,
                     sBox, diag, entries, cnt);
  hipLaunchKernelGGL(k_scan, dim3(NB), dim3(512), 0, stream,
                     diag, entries, cnt, posm, sScore, sIdx, out);
}